// Round 1
// 330.333 us; speedup vs baseline: 1.0429x; 1.0429x over previous
//
#include <hip/hip_runtime.h>
#include <hip/hip_fp16.h>
#include <math.h>

typedef _Float16 half8 __attribute__((ext_vector_type(8)));
typedef __fp16 fp16x2 __attribute__((ext_vector_type(2)));
typedef float f32x4 __attribute__((ext_vector_type(4)));

#define BATCH 1024
#define IN_DIM 4096
#define HV 8192
#define NTAP 40          // 39 gates -> degree-39 polynomial -> 40 taps

#define BM 128
#define BN 128
#define BK 32
#define BKP 36           // f32 fallback LDS row stride

#define GLD16(g, l) __builtin_amdgcn_global_load_lds(                          \
    (const __attribute__((address_space(1))) void*)(g),                        \
    (__attribute__((address_space(3))) void*)(l), 16, 0, 0)

// pack 8 f32 -> 8 f16 (RTZ), 4 VALU instrs (fallback path only)
static __device__ __forceinline__ half8 pk8(f32x4 a, f32x4 b) {
    union { fp16x2 p[4]; half8 h; } u;
    u.p[0] = __builtin_amdgcn_cvt_pkrtz(a.x, a.y);
    u.p[1] = __builtin_amdgcn_cvt_pkrtz(a.z, a.w);
    u.p[2] = __builtin_amdgcn_cvt_pkrtz(b.x, b.y);
    u.p[3] = __builtin_amdgcn_cvt_pkrtz(b.z, b.w);
    return u.h;
}

// ---------------- f32 -> f16 conversion (RNE) ----------------
typedef _Float16 half4v __attribute__((ext_vector_type(4)));
__global__ __launch_bounds__(256) void cvt_f32_f16(const float4* __restrict__ src,
                                                   half4v* __restrict__ dst, int n4) {
    int i = blockIdx.x * 256 + threadIdx.x;
    if (i < n4) {
        float4 v = src[i];
        half4v h;
        h.x = (_Float16)v.x; h.y = (_Float16)v.y;
        h.z = (_Float16)v.z; h.w = (_Float16)v.w;
        dst[i] = h;
    }
}

// ---------------- gate-polynomial taps, computed once (1 block, 1 wave) ----------------
// tap k = Re(coeff of shift^k) of prod_t (cos(a_t/2) + i sin(a_t/2) * shift)
__global__ __launch_bounds__(64) void compute_taps(const float* __restrict__ qp,
                                                   float* __restrict__ taps) {
    const int lane = threadIdx.x;
    float qv = (lane < 39) ? qp[lane] : 0.f;
    float pr = (lane == 0) ? 1.f : 0.f;
    float pim = 0.f;
    for (int t = 0; t < 39; t++) {
        float a = __shfl(qv, t, 64) * 0.5f;
        float c = cosf(a), s = sinf(a);
        float ur = __shfl_up(pr, 1, 64);
        float ui = __shfl_up(pim, 1, 64);
        if (lane == 0) { ur = 0.f; ui = 0.f; }
        float nr = c * pr - s * ui;
        float ni = c * pim + s * ur;
        pr = nr; pim = ni;
    }
    if (lane < NTAP) taps[lane] = pr;       // only real parts needed downstream
}

// ---------------- primary GEMM: f16 inputs, GLD16 staging, swizzled LDS ----------------
// out[m*HV + n] = sum_k A[m][k] * B[n][k]
// 512 threads = 8 waves (2M x 4N), each wave owns a 64x32 output sub-tile.
// LDS swizzle: 16B slot s of row R holds global K-chunk s ^ ((R>>1)&3).
//   - staging: linear LDS dest (GLD16 requirement), inverse-swizzled GLOBAL source
//   - read: slot = q ^ ((R>>1)&3)
//   => for fixed q the 16 r-lanes spread 2-per-4-bank-group (2-way = free) instead of 8-way.
__global__ __launch_bounds__(512, 4) void gemm_f16(
        const _Float16* __restrict__ A,   // [BATCH][IN_DIM] f16
        const _Float16* __restrict__ B,   // [HV][IN_DIM]   f16
        float* __restrict__ out,          // classical [BATCH][HV]
        long out_n) {
    __shared__ __align__(16) _Float16 lgA[BM * BK];   // 8 KB
    __shared__ __align__(16) _Float16 lgB[BN * BK];   // 8 KB

    const int tid  = threadIdx.x;
    const int lane = tid & 63;
    const int wave = tid >> 6;          // 0..7
    const int wm = wave & 1;            // 2 waves in M (64 rows each)
    const int wn = wave >> 1;           // 4 waves in N (32 cols each)
    const int q = lane >> 4, r = lane & 15;
    const int bm = blockIdx.y * BM;
    const int bn = blockIdx.x * BN;

    // staging: thread t owns LDS bytes [t*16, t*16+16) of each 8 KB tile
    //   -> LDS row = t>>2, linear slot = t&3; source chunk = (t&3) ^ ((row>>1)&3)
    const int srow  = tid >> 2;                        // 0..127
    const int sslot = (tid & 3) ^ ((srow >> 1) & 3);   // inverse-swizzled source slot
    const _Float16* gA = A + (size_t)(bm + srow) * IN_DIM + sslot * 8;
    const _Float16* gB = B + (size_t)(bn + srow) * IN_DIM + sslot * 8;
    _Float16* lA = &lgA[(wave * 16) * BK];   // wave-uniform base; lane*16B appended by HW
    _Float16* lB = &lgB[(wave * 16) * BK];

    f32x4 acc[4][2] = {};

    for (int k0 = 0; k0 < IN_DIM; k0 += BK) {
        GLD16(gA + k0, lA);
        GLD16(gB + k0, lB);
        __syncthreads();   // drains vmcnt: tile staged

        half8 af[4], bf[2];
        #pragma unroll
        for (int i = 0; i < 4; i++) {
            const int R = wm * 64 + i * 16 + r;
            af[i] = *(const half8*)&lgA[R * BK + ((q ^ ((R >> 1) & 3)) * 8)];
        }
        #pragma unroll
        for (int j = 0; j < 2; j++) {
            const int R = wn * 32 + j * 16 + r;
            bf[j] = *(const half8*)&lgB[R * BK + ((q ^ ((R >> 1) & 3)) * 8)];
        }

        #pragma unroll
        for (int i = 0; i < 4; i++)
            #pragma unroll
            for (int j = 0; j < 2; j++)
                acc[i][j] = __builtin_amdgcn_mfma_f32_16x16x32_f16(af[i], bf[j], acc[i][j], 0, 0, 0);
        __syncthreads();   // all fragment reads done before next staging overwrites
    }

    // C/D layout: col = lane&15, row = (lane>>4)*4 + reg.  Guarded stores.
    #pragma unroll
    for (int i = 0; i < 4; i++) {
        const int row = bm + wm * 64 + i * 16 + q * 4;
        #pragma unroll
        for (int j = 0; j < 2; j++) {
            const int col = bn + wn * 32 + j * 16 + r;
            #pragma unroll
            for (int reg = 0; reg < 4; reg++) {
                long idx = (long)(row + reg) * HV + col;
                if (idx < out_n) out[idx] = acc[i][j][reg];
            }
        }
    }
}

// ---------------- fallback GEMM: f32 inputs, register staging (R6, proven) ----------------
__global__ __launch_bounds__(256) void gemm_f32in(
        const float* __restrict__ A, const float* __restrict__ B,
        float* __restrict__ out, long out_n) {
    __shared__ __align__(16) float lgA[BM * BKP];
    __shared__ __align__(16) float lgB[BN * BKP];

    const int tid  = threadIdx.x;
    const int lane = tid & 63;
    const int wave = tid >> 6;
    const int wm = wave & 1, wn = wave >> 1;
    const int q = lane >> 4, r = lane & 15;
    const int bm = blockIdx.y * BM;
    const int bn = blockIdx.x * BN;

    const int rg = lane >> 3;
    const int cg = (lane & 7) * 4;
    const float* gA = A + (size_t)(bm + wave * 32 + rg) * IN_DIM + cg;
    const float* gB = B + (size_t)(bn + wave * 32 + rg) * IN_DIM + cg;
    float* lA = &lgA[(wave * 32 + rg) * BKP + cg];
    float* lB = &lgB[(wave * 32 + rg) * BKP + cg];

    f32x4 acc[4][4] = {};

    for (int k0 = 0; k0 < IN_DIM; k0 += BK) {
        float4 va[4], vb[4];
        #pragma unroll
        for (int i = 0; i < 4; i++) {
            va[i] = *(const float4*)(gA + k0 + (size_t)(8 * i) * IN_DIM);
            vb[i] = *(const float4*)(gB + k0 + (size_t)(8 * i) * IN_DIM);
        }
        __syncthreads();
        #pragma unroll
        for (int i = 0; i < 4; i++) {
            *(float4*)(lA + 8 * i * BKP) = va[i];
            *(float4*)(lB + 8 * i * BKP) = vb[i];
        }
        __syncthreads();

        half8 af[4], bf[4];
        #pragma unroll
        for (int i = 0; i < 4; i++) {
            const float* p = &lgA[(wm * 64 + i * 16 + r) * BKP + q * 8];
            af[i] = pk8(*(const f32x4*)p, *(const f32x4*)(p + 4));
        }
        #pragma unroll
        for (int j = 0; j < 4; j++) {
            const float* p = &lgB[(wn * 64 + j * 16 + r) * BKP + q * 8];
            bf[j] = pk8(*(const f32x4*)p, *(const f32x4*)(p + 4));
        }

        #pragma unroll
        for (int i = 0; i < 4; i++)
            #pragma unroll
            for (int j = 0; j < 4; j++)
                acc[i][j] = __builtin_amdgcn_mfma_f32_16x16x32_f16(af[i], bf[j], acc[i][j], 0, 0, 0);
    }

    #pragma unroll
    for (int i = 0; i < 4; i++) {
        const int row = bm + wm * 64 + i * 16 + q * 4;
        #pragma unroll
        for (int j = 0; j < 4; j++) {
            const int col = bn + wn * 64 + j * 16 + r;
            #pragma unroll
            for (int reg = 0; reg < 4; reg++) {
                long idx = (long)(row + reg) * HV + col;
                if (idx < out_n) out[idx] = acc[i][j][reg];
            }
        }
    }
}

// ---------------- fused normalize + real-part 40-tap circular conv, in place ----------------
__global__ __launch_bounds__(256) void norm_conv(float* __restrict__ out,
                                                 const float* __restrict__ qp,
                                                 const float* __restrict__ taps,
                                                 long out_n) {
    __shared__ __align__(16) float ldsv[HV + 48];
    __shared__ float scr[NTAP];
    __shared__ float red[4];

    const int b = blockIdx.x;
    if ((long)(b + 1) * HV > out_n) return;

    const int tid = threadIdx.x;
    const int lane = tid & 63;
    const int wave = tid >> 6;
    float* rowp = out + (size_t)b * HV;
    const float4* row4 = (const float4*)rowp;
    float4* l4 = (float4*)ldsv;

    float ss = 0.f;
    #pragma unroll
    for (int it = 0; it < 8; it++) {
        int j = it * 256 + tid;
        float4 v = row4[j];
        ss += v.x * v.x + v.y * v.y + v.z * v.z + v.w * v.w;
        l4[10 + j] = v;                         // NTAP/4 = 10
    }
    if (tid < NTAP) ldsv[tid] = rowp[HV - NTAP + tid];

    #pragma unroll
    for (int off = 32; off > 0; off >>= 1) ss += __shfl_down(ss, off, 64);
    if (lane == 0) red[wave] = ss;

    if (taps) {
        if (tid < NTAP) scr[tid] = taps[tid];   // precomputed by compute_taps
    } else if (wave == 0) {
        // fallback: in-kernel serial gate polynomial (only if no workspace for taps)
        float qv = (lane < 39) ? qp[lane] : 0.f;
        float pr = (lane == 0) ? 1.f : 0.f;
        float pim = 0.f;
        for (int t = 0; t < 39; t++) {
            float a = __shfl(qv, t, 64) * 0.5f;
            float c = cosf(a), s = sinf(a);
            float ur = __shfl_up(pr, 1, 64);
            float ui = __shfl_up(pim, 1, 64);
            if (lane == 0) { ur = 0.f; ui = 0.f; }
            float nr = c * pr - s * ui;
            float ni = c * pim + s * ur;
            pr = nr; pim = ni;
        }
        if (lane < NTAP) scr[lane] = pr;        // only real parts needed
    }
    __syncthreads();

    const float inv = 1.0f / sqrtf(red[0] + red[1] + red[2] + red[3]);
    float rc[NTAP];
    #pragma unroll
    for (int k = 0; k < NTAP; k++) rc[k] = scr[k] * inv;

    float4* out4 = (float4*)rowp;
    #pragma unroll
    for (int it = 0; it < 8; it++) {
        const int i0 = (it * 256 + tid) * 4;
        float w[48];
        #pragma unroll
        for (int t = 0; t < 12; t++) ((float4*)w)[t] = l4[(i0 >> 2) + t];

        float ar[4] = {0.f, 0.f, 0.f, 0.f};
        #pragma unroll
        for (int k = 0; k < NTAP; k++) {
            const float c0 = rc[k];
            #pragma unroll
            for (int o = 0; o < 4; o++)
                ar[o] += c0 * w[o + NTAP - k];
        }
        out4[i0 >> 2] = make_float4(ar[0], ar[1], ar[2], ar[3]);
    }
}

// ---------------- launch ----------------
extern "C" void kernel_launch(void* const* d_in, const int* in_sizes, int n_in,
                              void* d_out, int out_size, void* d_ws, size_t ws_size,
                              hipStream_t stream) {
    const float* x  = (const float*)d_in[0];   // [1024][4096]
    const float* W  = (const float*)d_in[1];   // [8192][4096]
    const float* qp = (const float*)d_in[2];   // [39]
    float* out = (float*)d_out;                // [1024][8192] floats (Re of amps)
    long out_n = (long)out_size;

    const size_t need = (size_t)BATCH * IN_DIM * 2 + (size_t)HV * IN_DIM * 2;  // 72 MB
    dim3 grid(HV / BN, BATCH / BM);            // (64, 8)

    if (ws_size >= need) {
        _Float16* xh = (_Float16*)d_ws;
        _Float16* wh = xh + (size_t)BATCH * IN_DIM;
        float* taps = nullptr;
        if (ws_size >= need + 256) {
            taps = (float*)((char*)d_ws + need);
            compute_taps<<<1, 64, 0, stream>>>(qp, taps);
        }
        int n4x = BATCH * IN_DIM / 4;          // 1,048,576
        int n4w = HV * IN_DIM / 4;             // 8,388,608
        cvt_f32_f16<<<n4x / 256, 256, 0, stream>>>((const float4*)x, (half4v*)xh, n4x);
        cvt_f32_f16<<<n4w / 256, 256, 0, stream>>>((const float4*)W, (half4v*)wh, n4w);
        gemm_f16<<<grid, 512, 0, stream>>>(xh, wh, out, out_n);
        norm_conv<<<BATCH, 256, 0, stream>>>(out, qp, taps, out_n);
    } else {
        float* taps = nullptr;
        if (ws_size >= 256) {
            taps = (float*)d_ws;
            compute_taps<<<1, 64, 0, stream>>>(qp, taps);
        }
        gemm_f32in<<<grid, 256, 0, stream>>>(x, W, out, out_n);
        norm_conv<<<BATCH, 256, 0, stream>>>(out, qp, taps, out_n);
    }
}

// Round 4
// 321.193 us; speedup vs baseline: 1.0726x; 1.0285x over previous
//
#include <hip/hip_runtime.h>
#include <hip/hip_fp16.h>
#include <math.h>

typedef _Float16 half8 __attribute__((ext_vector_type(8)));
typedef __fp16 fp16x2 __attribute__((ext_vector_type(2)));
typedef float f32x4 __attribute__((ext_vector_type(4)));

#define BATCH 1024
#define IN_DIM 4096
#define HV 8192
#define NTAP 40          // 39 gates -> degree-39 polynomial -> 40 taps

#define BM 128
#define BN 128
#define BK 32
#define BKP 36           // f32 fallback LDS row stride

#define GLD16(g, l) __builtin_amdgcn_global_load_lds(                          \
    (const __attribute__((address_space(1))) void*)(g),                        \
    (__attribute__((address_space(3))) void*)(l), 16, 0, 0)

// pack 8 f32 -> 8 f16 (RTZ), 4 VALU instrs (fallback path only)
static __device__ __forceinline__ half8 pk8(f32x4 a, f32x4 b) {
    union { fp16x2 p[4]; half8 h; } u;
    u.p[0] = __builtin_amdgcn_cvt_pkrtz(a.x, a.y);
    u.p[1] = __builtin_amdgcn_cvt_pkrtz(a.z, a.w);
    u.p[2] = __builtin_amdgcn_cvt_pkrtz(b.x, b.y);
    u.p[3] = __builtin_amdgcn_cvt_pkrtz(b.z, b.w);
    return u.h;
}

// ---------------- f32 -> f16 conversion (RNE) ----------------
typedef _Float16 half4v __attribute__((ext_vector_type(4)));
__global__ __launch_bounds__(256) void cvt_f32_f16(const float4* __restrict__ src,
                                                   half4v* __restrict__ dst, int n4) {
    int i = blockIdx.x * 256 + threadIdx.x;
    if (i < n4) {
        float4 v = src[i];
        half4v h;
        h.x = (_Float16)v.x; h.y = (_Float16)v.y;
        h.z = (_Float16)v.z; h.w = (_Float16)v.w;
        dst[i] = h;
    }
}

// ---------------- gate-polynomial taps, computed once (1 block, 1 wave) ----------------
__global__ __launch_bounds__(64) void compute_taps(const float* __restrict__ qp,
                                                   float* __restrict__ taps) {
    const int lane = threadIdx.x;
    float qv = (lane < 39) ? qp[lane] : 0.f;
    float pr = (lane == 0) ? 1.f : 0.f;
    float pim = 0.f;
    for (int t = 0; t < 39; t++) {
        float a = __shfl(qv, t, 64) * 0.5f;
        float c = cosf(a), s = sinf(a);
        float ur = __shfl_up(pr, 1, 64);
        float ui = __shfl_up(pim, 1, 64);
        if (lane == 0) { ur = 0.f; ui = 0.f; }
        float nr = c * pr - s * ui;
        float ni = c * pim + s * ur;
        pr = nr; pim = ni;
    }
    if (lane < NTAP) taps[lane] = pr;       // only real parts needed downstream
}

// ---------------- primary GEMM: f16, GLD16 staging, swizzled LDS, 2-phase dbuf ----------
// 256 threads = 4 waves (2M x 2N), each wave owns a 64x64 output tile (acc[4][4]).
//   - halves LDS-read amplification vs 8-wave 64x32 (2.1 GB vs 3.2 GB total)
//   - double-buffered LDS: stage tile t+1 BEFORE computing tile t (T3 minimum 2-phase),
//     one barrier per K-step; load latency hides under ds_read+MFMA + 2-block stagger
// LDS swizzle (verified R1, conflicts -> 0): linear slot s of row R holds K-chunk
//   s ^ ((R>>1)&3); GLD16 dest linear, global source inverse-swizzled.
__global__ __launch_bounds__(256, 2) void gemm_f16(
        const _Float16* __restrict__ A,   // [BATCH][IN_DIM] f16
        const _Float16* __restrict__ B,   // [HV][IN_DIM]   f16
        float* __restrict__ out,          // classical [BATCH][HV]
        long out_n) {
    __shared__ __align__(16) _Float16 lgA[2][BM * BK];   // 2 x 8 KB
    __shared__ __align__(16) _Float16 lgB[2][BN * BK];   // 2 x 8 KB

    const int tid  = threadIdx.x;
    const int lane = tid & 63;
    const int wave = tid >> 6;          // 0..3
    const int wm = wave & 1;            // 2 waves in M (64 rows each)
    const int wn = wave >> 1;           // 2 waves in N (64 cols each)
    const int q = lane >> 4, r = lane & 15;
    const int bm = blockIdx.y * BM;
    const int bn = blockIdx.x * BN;

    // staging: 256 threads x 16B cover 8 KB; each tile needs 2 chunks/thread
    // chunk set 0: row = tid>>2 (0..63); set 1: row+64 (same swizzle bits)
    const int srow  = tid >> 2;
    const int sslot = (tid & 3) ^ ((srow >> 1) & 3);   // inverse-swizzled source slot
    const _Float16* gA0 = A + (size_t)(bm + srow) * IN_DIM + sslot * 8;
    const _Float16* gA1 = gA0 + (size_t)64 * IN_DIM;
    const _Float16* gB0 = B + (size_t)(bn + srow) * IN_DIM + sslot * 8;
    const _Float16* gB1 = gB0 + (size_t)64 * IN_DIM;
    const int d0 = (wave * 16) * BK;        // wave-uniform LDS elem offset; HW adds lane*16B
    const int d1 = (64 + wave * 16) * BK;

    f32x4 acc[4][4] = {};

#define STAGE(buf, k0)  do {                         \
        GLD16(gA0 + (k0), &lgA[buf][d0]);            \
        GLD16(gA1 + (k0), &lgA[buf][d1]);            \
        GLD16(gB0 + (k0), &lgB[buf][d0]);            \
        GLD16(gB1 + (k0), &lgB[buf][d1]);            \
    } while (0)

#define COMPUTE(buf)  do {                                                         \
        half8 af[4], bf[4];                                                        \
        _Pragma("unroll")                                                          \
        for (int i = 0; i < 4; i++) {                                              \
            const int R = wm * 64 + i * 16 + r;                                    \
            af[i] = *(const half8*)&lgA[buf][R * BK + ((q ^ ((R >> 1) & 3)) * 8)]; \
        }                                                                          \
        _Pragma("unroll")                                                          \
        for (int j = 0; j < 4; j++) {                                              \
            const int R = wn * 64 + j * 16 + r;                                    \
            bf[j] = *(const half8*)&lgB[buf][R * BK + ((q ^ ((R >> 1) & 3)) * 8)]; \
        }                                                                          \
        _Pragma("unroll")                                                          \
        for (int i = 0; i < 4; i++)                                                \
            _Pragma("unroll")                                                      \
            for (int j = 0; j < 4; j++)                                            \
                acc[i][j] = __builtin_amdgcn_mfma_f32_16x16x32_f16(af[i], bf[j], acc[i][j], 0, 0, 0); \
    } while (0)

    STAGE(0, 0);
    __syncthreads();                 // buf0 staged (compiler drains vmcnt before barrier)
    for (int k0 = 0; k0 < IN_DIM; k0 += 2 * BK) {        // IN_DIM/BK = 128, even
        STAGE(1, k0 + BK);           // prefetch next tile into buf1 (always in range)
        COMPUTE(0);                  // overlap: loads in flight during ds_read + MFMA
        __syncthreads();             // drains vmcnt: buf1 ready, buf0 reads done
        if (k0 + 2 * BK < IN_DIM) STAGE(0, k0 + 2 * BK);
        COMPUTE(1);
        __syncthreads();
    }
#undef STAGE
#undef COMPUTE

    // C/D layout: col = lane&15, row = (lane>>4)*4 + reg.  Guarded stores.
    #pragma unroll
    for (int i = 0; i < 4; i++) {
        const int row = bm + wm * 64 + i * 16 + q * 4;
        #pragma unroll
        for (int j = 0; j < 4; j++) {
            const int col = bn + wn * 64 + j * 16 + r;
            #pragma unroll
            for (int reg = 0; reg < 4; reg++) {
                long idx = (long)(row + reg) * HV + col;
                if (idx < out_n) out[idx] = acc[i][j][reg];
            }
        }
    }
}

// ---------------- fallback GEMM: f32 inputs, register staging (R6, proven) ----------------
__global__ __launch_bounds__(256) void gemm_f32in(
        const float* __restrict__ A, const float* __restrict__ B,
        float* __restrict__ out, long out_n) {
    __shared__ __align__(16) float lgA[BM * BKP];
    __shared__ __align__(16) float lgB[BN * BKP];

    const int tid  = threadIdx.x;
    const int lane = tid & 63;
    const int wave = tid >> 6;
    const int wm = wave & 1, wn = wave >> 1;
    const int q = lane >> 4, r = lane & 15;
    const int bm = blockIdx.y * BM;
    const int bn = blockIdx.x * BN;

    const int rg = lane >> 3;
    const int cg = (lane & 7) * 4;
    const float* gA = A + (size_t)(bm + wave * 32 + rg) * IN_DIM + cg;
    const float* gB = B + (size_t)(bn + wave * 32 + rg) * IN_DIM + cg;
    float* lA = &lgA[(wave * 32 + rg) * BKP + cg];
    float* lB = &lgB[(wave * 32 + rg) * BKP + cg];

    f32x4 acc[4][4] = {};

    for (int k0 = 0; k0 < IN_DIM; k0 += BK) {
        float4 va[4], vb[4];
        #pragma unroll
        for (int i = 0; i < 4; i++) {
            va[i] = *(const float4*)(gA + k0 + (size_t)(8 * i) * IN_DIM);
            vb[i] = *(const float4*)(gB + k0 + (size_t)(8 * i) * IN_DIM);
        }
        __syncthreads();
        #pragma unroll
        for (int i = 0; i < 4; i++) {
            *(float4*)(lA + 8 * i * BKP) = va[i];
            *(float4*)(lB + 8 * i * BKP) = vb[i];
        }
        __syncthreads();

        half8 af[4], bf[4];
        #pragma unroll
        for (int i = 0; i < 4; i++) {
            const float* p = &lgA[(wm * 64 + i * 16 + r) * BKP + q * 8];
            af[i] = pk8(*(const f32x4*)p, *(const f32x4*)(p + 4));
        }
        #pragma unroll
        for (int j = 0; j < 4; j++) {
            const float* p = &lgB[(wn * 64 + j * 16 + r) * BKP + q * 8];
            bf[j] = pk8(*(const f32x4*)p, *(const f32x4*)(p + 4));
        }

        #pragma unroll
        for (int i = 0; i < 4; i++)
            #pragma unroll
            for (int j = 0; j < 4; j++)
                acc[i][j] = __builtin_amdgcn_mfma_f32_16x16x32_f16(af[i], bf[j], acc[i][j], 0, 0, 0);
    }

    #pragma unroll
    for (int i = 0; i < 4; i++) {
        const int row = bm + wm * 64 + i * 16 + q * 4;
        #pragma unroll
        for (int j = 0; j < 4; j++) {
            const int col = bn + wn * 64 + j * 16 + r;
            #pragma unroll
            for (int reg = 0; reg < 4; reg++) {
                long idx = (long)(row + reg) * HV + col;
                if (idx < out_n) out[idx] = acc[i][j][reg];
            }
        }
    }
}

// ---------------- fused normalize + real-part 40-tap circular conv, in place ----------------
// 32 contiguous outputs/thread -> LDS reads drop from 12 to 2.25 floats/output;
// XOR-swizzled LDS (lane stride is 128B -> would be full bank collision un-swizzled);
// taps broadcast from LDS inside k-loop; inv folded at store.
#define SW4(p4) ((p4) ^ (((p4) >> 3) & 7))
__global__ __launch_bounds__(256) void norm_conv(float* __restrict__ out,
                                                 const float* __restrict__ qp,
                                                 const float* __restrict__ taps,
                                                 long out_n) {
    __shared__ __align__(16) float ldsv[40 + HV + 24];   // logical [p] = row[(p-40) mod HV]
    __shared__ float scr[NTAP];
    __shared__ float red[4];

    const int b = blockIdx.x;
    if ((long)(b + 1) * HV > out_n) return;

    const int tid = threadIdx.x;
    const int lane = tid & 63;
    const int wave = tid >> 6;
    float* rowp = out + (size_t)b * HV;
    const float4* row4 = (const float4*)rowp;
    float4* l4 = (float4*)ldsv;

    float ss = 0.f;
    #pragma unroll
    for (int it = 0; it < 8; it++) {
        int j = it * 256 + tid;
        float4 v = row4[j];
        ss += v.x * v.x + v.y * v.y + v.z * v.z + v.w * v.w;
        l4[SW4(10 + j)] = v;                    // logical float4 index 10+j, swizzled
    }
    if (tid < NTAP) {                           // circular halo: logical p = tid (0..39)
        ldsv[(SW4(tid >> 2) << 2) | (tid & 3)] = rowp[HV - NTAP + tid];
    }

    #pragma unroll
    for (int off = 32; off > 0; off >>= 1) ss += __shfl_down(ss, off, 64);
    if (lane == 0) red[wave] = ss;

    if (taps) {
        if (tid < NTAP) scr[tid] = taps[tid];   // precomputed by compute_taps
    } else if (wave == 0) {
        float qv = (lane < 39) ? qp[lane] : 0.f;
        float pr = (lane == 0) ? 1.f : 0.f;
        float pim = 0.f;
        for (int t = 0; t < 39; t++) {
            float a = __shfl(qv, t, 64) * 0.5f;
            float c = cosf(a), s = sinf(a);
            float ur = __shfl_up(pr, 1, 64);
            float ui = __shfl_up(pim, 1, 64);
            if (lane == 0) { ur = 0.f; ui = 0.f; }
            float nr = c * pr - s * ui;
            float ni = c * pim + s * ur;
            pr = nr; pim = ni;
        }
        if (lane < NTAP) scr[lane] = pr;
    }
    __syncthreads();

    const float inv = 1.0f / sqrtf(red[0] + red[1] + red[2] + red[3]);

    // window: logical ldsv[i0 .. i0+71] covers in[i0-40 .. i0+31]; out[i0+o] needs w[40+o-k]
    float w[72];
    #pragma unroll
    for (int t = 0; t < 18; t++) ((float4*)w)[t] = l4[SW4(8 * tid + t)];

    float4* out4 = (float4*)rowp;
    #pragma unroll
    for (int h = 0; h < 2; h++) {               // two half-passes keep VGPR ~100
        float av[16] = {};
        #pragma unroll
        for (int k = 0; k < NTAP; k++) {
            const float c = scr[k];             // LDS broadcast (free)
            #pragma unroll
            for (int o = 0; o < 16; o++) av[o] += c * w[40 + h * 16 + o - k];
        }
        #pragma unroll
        for (int t = 0; t < 4; t++) {
            out4[8 * tid + 4 * h + t] = make_float4(inv * av[4 * t], inv * av[4 * t + 1],
                                                    inv * av[4 * t + 2], inv * av[4 * t + 3]);
        }
    }
}

// ---------------- launch ----------------
extern "C" void kernel_launch(void* const* d_in, const int* in_sizes, int n_in,
                              void* d_out, int out_size, void* d_ws, size_t ws_size,
                              hipStream_t stream) {
    const float* x  = (const float*)d_in[0];   // [1024][4096]
    const float* W  = (const float*)d_in[1];   // [8192][4096]
    const float* qp = (const float*)d_in[2];   // [39]
    float* out = (float*)d_out;                // [1024][8192] floats (Re of amps)
    long out_n = (long)out_size;

    const size_t need = (size_t)BATCH * IN_DIM * 2 + (size_t)HV * IN_DIM * 2;  // 72 MB
    dim3 grid(HV / BN, BATCH / BM);            // (64, 8)

    if (ws_size >= need) {
        _Float16* xh = (_Float16*)d_ws;
        _Float16* wh = xh + (size_t)BATCH * IN_DIM;
        float* taps = nullptr;
        if (ws_size >= need + 256) {
            taps = (float*)((char*)d_ws + need);
            compute_taps<<<1, 64, 0, stream>>>(qp, taps);
        }
        int n4x = BATCH * IN_DIM / 4;          // 1,048,576
        int n4w = HV * IN_DIM / 4;             // 8,388,608
        cvt_f32_f16<<<n4x / 256, 256, 0, stream>>>((const float4*)x, (half4v*)xh, n4x);
        cvt_f32_f16<<<n4w / 256, 256, 0, stream>>>((const float4*)W, (half4v*)wh, n4w);
        gemm_f16<<<grid, 256, 0, stream>>>(xh, wh, out, out_n);
        norm_conv<<<BATCH, 256, 0, stream>>>(out, qp, taps, out_n);
    } else {
        float* taps = nullptr;
        if (ws_size >= 256) {
            taps = (float*)d_ws;
            compute_taps<<<1, 64, 0, stream>>>(qp, taps);
        }
        gemm_f32in<<<grid, 256, 0, stream>>>(x, W, out, out_n);
        norm_conv<<<BATCH, 256, 0, stream>>>(out, qp, taps, out_n);
    }
}

// Round 5
// 303.540 us; speedup vs baseline: 1.1350x; 1.0582x over previous
//
#include <hip/hip_runtime.h>
#include <hip/hip_fp16.h>
#include <math.h>

typedef _Float16 half8 __attribute__((ext_vector_type(8)));
typedef __fp16 fp16x2 __attribute__((ext_vector_type(2)));
typedef float f32x4 __attribute__((ext_vector_type(4)));

#define BATCH 1024
#define IN_DIM 4096
#define HV 8192
#define NTAP 40          // 39 gates -> degree-39 polynomial -> 40 taps

#define BM 128
#define BN 128
#define BK 32
#define BKP 36           // f32 fallback LDS row stride

// pipelined gemm geometry
#define BM2 128
#define BN2 256
#define BK2 64
#define NT2 (IN_DIM / BK2)       // 64 K-tiles
#define ASZ (BM2 * BK2)          // 8192 f16 (16 KB)
#define BSZ (BN2 * BK2)          // 16384 f16 (32 KB)
#define TSZ (ASZ + BSZ)          // 24576 f16 (48 KB) per buffer

#define GLD16(g, l) __builtin_amdgcn_global_load_lds(                          \
    (const __attribute__((address_space(1))) void*)(g),                        \
    (__attribute__((address_space(3))) void*)(l), 16, 0, 0)

// pack 8 f32 -> 8 f16 (RTZ), 4 VALU instrs (fallback path only)
static __device__ __forceinline__ half8 pk8(f32x4 a, f32x4 b) {
    union { fp16x2 p[4]; half8 h; } u;
    u.p[0] = __builtin_amdgcn_cvt_pkrtz(a.x, a.y);
    u.p[1] = __builtin_amdgcn_cvt_pkrtz(a.z, a.w);
    u.p[2] = __builtin_amdgcn_cvt_pkrtz(b.x, b.y);
    u.p[3] = __builtin_amdgcn_cvt_pkrtz(b.z, b.w);
    return u.h;
}

// ---------------- f32 -> f16 conversion (RNE) ----------------
typedef _Float16 half4v __attribute__((ext_vector_type(4)));
__global__ __launch_bounds__(256) void cvt_f32_f16(const float4* __restrict__ src,
                                                   half4v* __restrict__ dst, int n4) {
    int i = blockIdx.x * 256 + threadIdx.x;
    if (i < n4) {
        float4 v = src[i];
        half4v h;
        h.x = (_Float16)v.x; h.y = (_Float16)v.y;
        h.z = (_Float16)v.z; h.w = (_Float16)v.w;
        dst[i] = h;
    }
}

// ---------------- gate-polynomial taps, computed once (1 block, 1 wave) ----------------
__global__ __launch_bounds__(64) void compute_taps(const float* __restrict__ qp,
                                                   float* __restrict__ taps) {
    const int lane = threadIdx.x;
    float qv = (lane < 39) ? qp[lane] : 0.f;
    float pr = (lane == 0) ? 1.f : 0.f;
    float pim = 0.f;
    for (int t = 0; t < 39; t++) {
        float a = __shfl(qv, t, 64) * 0.5f;
        float c = cosf(a), s = sinf(a);
        float ur = __shfl_up(pr, 1, 64);
        float ui = __shfl_up(pim, 1, 64);
        if (lane == 0) { ur = 0.f; ui = 0.f; }
        float nr = c * pr - s * ui;
        float ni = c * pim + s * ur;
        pr = nr; pim = ni;
    }
    if (lane < NTAP) taps[lane] = pr;       // only real parts needed downstream
}

// ---------------- primary GEMM: counted-vmcnt triple-buffer pipeline (T3+T4+T5) --------
// 128(M) x 256(N) tile, BK=64, 512 threads = 8 waves (2M x 4N), 64x64 per wave.
// Grid 32x8 = 256 blocks = 1/CU.  LDS 3 x 48 KB buffers; 2 K-tiles of loads in flight.
// Main loop: s_waitcnt vmcnt(6) (tile t landed, t+1's 6 GLD16s stay in flight across
// the raw s_barrier) -> barrier -> issue STAGE(t+2) -> ds_read+MFMA(t).  vmcnt never
// drains to 0 until the last tile (T4).  One barrier per K-tile.
// Hazard: each wave's tile-t ds_reads complete (lgkmcnt, data-dep) before it reaches the
// iter-t+1 barrier; STAGE(t+2) into buf[(t+2)%3]=buf[(t-1)%3] is issued after that
// barrier, so it cannot overwrite LDS still being read.
// LDS swizzle: 8 16B-slots/row; physical slot = logical ^ (row&7); staging source
// pre-swizzled with the same XOR (involution), GLD16 dest linear (rule #21).
__global__ __launch_bounds__(512, 2) void gemm_f16(
        const _Float16* __restrict__ A,   // [BATCH][IN_DIM] f16
        const _Float16* __restrict__ B,   // [HV][IN_DIM]   f16
        float* __restrict__ out,          // classical [BATCH][HV]
        long out_n) {
    __shared__ __align__(16) _Float16 lds[3 * TSZ];   // 144 KB

    const int tid  = threadIdx.x;
    const int lane = tid & 63;
    const int wave = tid >> 6;          // 0..7
    const int wm = wave & 1;            // 2 waves in M (64 rows each)
    const int wn = wave >> 1;           // 4 waves in N (64 cols each)
    const int q = lane >> 4, r = lane & 15;
    const int bm = blockIdx.y * BM2;
    const int bn = blockIdx.x * BN2;

    // ---- staging addresses (fixed per thread; += k0 per tile) ----
    // A: 1024 slots of 16B, thread covers p = h*512+tid (h=0,1)
    // B: 2048 slots,        thread covers p = h*512+tid (h=0..3)
    // slot p -> row R=p>>3, physical slot s=p&7 holds source chunk c = s ^ (R&7)
    const _Float16* srcA[2];
    int dA[2];
    #pragma unroll
    for (int h = 0; h < 2; h++) {
        const int p = h * 512 + tid;
        const int R = p >> 3, c = (p & 7) ^ (R & 7);
        srcA[h] = A + (size_t)(bm + R) * IN_DIM + c * 8;
        dA[h] = (h * 512 + wave * 64) * 8;           // wave-uniform; HW adds lane*16B
    }
    const _Float16* srcB[4];
    int dB[4];
    #pragma unroll
    for (int h = 0; h < 4; h++) {
        const int p = h * 512 + tid;
        const int R = p >> 3, c = (p & 7) ^ (R & 7);
        srcB[h] = B + (size_t)(bn + R) * IN_DIM + c * 8;
        dB[h] = ASZ + (h * 512 + wave * 64) * 8;
    }

    f32x4 acc[4][4] = {};

#define STAGE(u, k0)  do {                                   \
        _Float16* bp = &lds[(u) * TSZ];                      \
        GLD16(srcA[0] + (k0), bp + dA[0]);                   \
        GLD16(srcA[1] + (k0), bp + dA[1]);                   \
        GLD16(srcB[0] + (k0), bp + dB[0]);                   \
        GLD16(srcB[1] + (k0), bp + dB[1]);                   \
        GLD16(srcB[2] + (k0), bp + dB[2]);                   \
        GLD16(srcB[3] + (k0), bp + dB[3]);                   \
    } while (0)

    // fragment LDS offsets: row R (stride 64 f16), logical slot s=kk*4+q,
    // physical slot s^(R&7) = s^(r&7) since 64|wm*64 and 16|i*16.
#define COMPUTE(u)  do {                                                            \
        const _Float16* bp = &lds[(u) * TSZ];                                       \
        half8 af[4][2], bf[4][2];                                                   \
        _Pragma("unroll")                                                           \
        for (int i = 0; i < 4; i++)                                                 \
            _Pragma("unroll")                                                       \
            for (int kk = 0; kk < 2; kk++) {                                        \
                const int R = wm * 64 + i * 16 + r;                                 \
                const int sw = (kk * 4 + q) ^ (r & 7);                              \
                af[i][kk] = *(const half8*)&bp[R * 64 + sw * 8];                    \
            }                                                                       \
        _Pragma("unroll")                                                           \
        for (int j = 0; j < 4; j++)                                                 \
            _Pragma("unroll")                                                       \
            for (int kk = 0; kk < 2; kk++) {                                        \
                const int R = wn * 64 + j * 16 + r;                                 \
                const int sw = (kk * 4 + q) ^ (r & 7);                              \
                bf[j][kk] = *(const half8*)&bp[ASZ + R * 64 + sw * 8];              \
            }                                                                       \
        __builtin_amdgcn_s_setprio(1);                                              \
        _Pragma("unroll")                                                           \
        for (int i = 0; i < 4; i++)                                                 \
            _Pragma("unroll")                                                       \
            for (int j = 0; j < 4; j++)                                             \
                _Pragma("unroll")                                                   \
                for (int kk = 0; kk < 2; kk++)                                      \
                    acc[i][j] = __builtin_amdgcn_mfma_f32_16x16x32_f16(             \
                        af[i][kk], bf[j][kk], acc[i][j], 0, 0, 0);                  \
        __builtin_amdgcn_s_setprio(0);                                              \
    } while (0)

    STAGE(0, 0);
    STAGE(1, BK2);
    int cur = 0;
    for (int t = 0; t < NT2 - 1; ++t) {
        asm volatile("s_waitcnt vmcnt(6)" ::: "memory");   // tile t landed; t+1 in flight
        __builtin_amdgcn_sched_barrier(0);
        __builtin_amdgcn_s_barrier();
        if (t + 2 < NT2) {
            const int nxt = (cur + 2 >= 3) ? cur - 1 : cur + 2;
            STAGE(nxt, (t + 2) * BK2);
        }
        COMPUTE(cur);
        cur = (cur + 1 == 3) ? 0 : cur + 1;
    }
    asm volatile("s_waitcnt vmcnt(0)" ::: "memory");       // final tile fully staged
    __builtin_amdgcn_sched_barrier(0);
    __builtin_amdgcn_s_barrier();
    COMPUTE(cur);
#undef STAGE
#undef COMPUTE

    // C/D layout: col = lane&15, row = (lane>>4)*4 + reg.  Guarded stores.
    #pragma unroll
    for (int i = 0; i < 4; i++) {
        const int row = bm + wm * 64 + i * 16 + q * 4;
        #pragma unroll
        for (int j = 0; j < 4; j++) {
            const int col = bn + wn * 64 + j * 16 + r;
            #pragma unroll
            for (int reg = 0; reg < 4; reg++) {
                long idx = (long)(row + reg) * HV + col;
                if (idx < out_n) out[idx] = acc[i][j][reg];
            }
        }
    }
}

// ---------------- fallback GEMM: f32 inputs, register staging (R6, proven) ----------------
__global__ __launch_bounds__(256) void gemm_f32in(
        const float* __restrict__ A, const float* __restrict__ B,
        float* __restrict__ out, long out_n) {
    __shared__ __align__(16) float lgA[BM * BKP];
    __shared__ __align__(16) float lgB[BN * BKP];

    const int tid  = threadIdx.x;
    const int lane = tid & 63;
    const int wave = tid >> 6;
    const int wm = wave & 1, wn = wave >> 1;
    const int q = lane >> 4, r = lane & 15;
    const int bm = blockIdx.y * BM;
    const int bn = blockIdx.x * BN;

    const int rg = lane >> 3;
    const int cg = (lane & 7) * 4;
    const float* gA = A + (size_t)(bm + wave * 32 + rg) * IN_DIM + cg;
    const float* gB = B + (size_t)(bn + wave * 32 + rg) * IN_DIM + cg;
    float* lA = &lgA[(wave * 32 + rg) * BKP + cg];
    float* lB = &lgB[(wave * 32 + rg) * BKP + cg];

    f32x4 acc[4][4] = {};

    for (int k0 = 0; k0 < IN_DIM; k0 += BK) {
        float4 va[4], vb[4];
        #pragma unroll
        for (int i = 0; i < 4; i++) {
            va[i] = *(const float4*)(gA + k0 + (size_t)(8 * i) * IN_DIM);
            vb[i] = *(const float4*)(gB + k0 + (size_t)(8 * i) * IN_DIM);
        }
        __syncthreads();
        #pragma unroll
        for (int i = 0; i < 4; i++) {
            *(float4*)(lA + 8 * i * BKP) = va[i];
            *(float4*)(lB + 8 * i * BKP) = vb[i];
        }
        __syncthreads();

        half8 af[4], bf[4];
        #pragma unroll
        for (int i = 0; i < 4; i++) {
            const float* p = &lgA[(wm * 64 + i * 16 + r) * BKP + q * 8];
            af[i] = pk8(*(const f32x4*)p, *(const f32x4*)(p + 4));
        }
        #pragma unroll
        for (int j = 0; j < 4; j++) {
            const float* p = &lgB[(wn * 64 + j * 16 + r) * BKP + q * 8];
            bf[j] = pk8(*(const f32x4*)p, *(const f32x4*)(p + 4));
        }

        #pragma unroll
        for (int i = 0; i < 4; i++)
            #pragma unroll
            for (int j = 0; j < 4; j++)
                acc[i][j] = __builtin_amdgcn_mfma_f32_16x16x32_f16(af[i], bf[j], acc[i][j], 0, 0, 0);
    }

    #pragma unroll
    for (int i = 0; i < 4; i++) {
        const int row = bm + wm * 64 + i * 16 + q * 4;
        #pragma unroll
        for (int j = 0; j < 4; j++) {
            const int col = bn + wn * 64 + j * 16 + r;
            #pragma unroll
            for (int reg = 0; reg < 4; reg++) {
                long idx = (long)(row + reg) * HV + col;
                if (idx < out_n) out[idx] = acc[i][j][reg];
            }
        }
    }
}

// ---------------- fused normalize + real-part 40-tap circular conv, in place ----------------
// 32 contiguous outputs/thread -> LDS reads 2.25 floats/output; XOR-swizzled LDS;
// taps broadcast from LDS; inv folded at store.  (R4: verified, ~10 us gain)
#define SW4(p4) ((p4) ^ (((p4) >> 3) & 7))
__global__ __launch_bounds__(256) void norm_conv(float* __restrict__ out,
                                                 const float* __restrict__ qp,
                                                 const float* __restrict__ taps,
                                                 long out_n) {
    __shared__ __align__(16) float ldsv[40 + HV + 24];   // logical [p] = row[(p-40) mod HV]
    __shared__ float scr[NTAP];
    __shared__ float red[4];

    const int b = blockIdx.x;
    if ((long)(b + 1) * HV > out_n) return;

    const int tid = threadIdx.x;
    const int lane = tid & 63;
    const int wave = tid >> 6;
    float* rowp = out + (size_t)b * HV;
    const float4* row4 = (const float4*)rowp;
    float4* l4 = (float4*)ldsv;

    float ss = 0.f;
    #pragma unroll
    for (int it = 0; it < 8; it++) {
        int j = it * 256 + tid;
        float4 v = row4[j];
        ss += v.x * v.x + v.y * v.y + v.z * v.z + v.w * v.w;
        l4[SW4(10 + j)] = v;                    // logical float4 index 10+j, swizzled
    }
    if (tid < NTAP) {                           // circular halo: logical p = tid (0..39)
        ldsv[(SW4(tid >> 2) << 2) | (tid & 3)] = rowp[HV - NTAP + tid];
    }

    #pragma unroll
    for (int off = 32; off > 0; off >>= 1) ss += __shfl_down(ss, off, 64);
    if (lane == 0) red[wave] = ss;

    if (taps) {
        if (tid < NTAP) scr[tid] = taps[tid];   // precomputed by compute_taps
    } else if (wave == 0) {
        float qv = (lane < 39) ? qp[lane] : 0.f;
        float pr = (lane == 0) ? 1.f : 0.f;
        float pim = 0.f;
        for (int t = 0; t < 39; t++) {
            float a = __shfl(qv, t, 64) * 0.5f;
            float c = cosf(a), s = sinf(a);
            float ur = __shfl_up(pr, 1, 64);
            float ui = __shfl_up(pim, 1, 64);
            if (lane == 0) { ur = 0.f; ui = 0.f; }
            float nr = c * pr - s * ui;
            float ni = c * pim + s * ur;
            pr = nr; pim = ni;
        }
        if (lane < NTAP) scr[lane] = pr;
    }
    __syncthreads();

    const float inv = 1.0f / sqrtf(red[0] + red[1] + red[2] + red[3]);

    // window: logical ldsv[i0 .. i0+71] covers in[i0-40 .. i0+31]; out[i0+o] needs w[40+o-k]
    float w[72];
    #pragma unroll
    for (int t = 0; t < 18; t++) ((float4*)w)[t] = l4[SW4(8 * tid + t)];

    float4* out4 = (float4*)rowp;
    #pragma unroll
    for (int h = 0; h < 2; h++) {               // two half-passes keep VGPR ~100
        float av[16] = {};
        #pragma unroll
        for (int k = 0; k < NTAP; k++) {
            const float c = scr[k];             // LDS broadcast (free)
            #pragma unroll
            for (int o = 0; o < 16; o++) av[o] += c * w[40 + h * 16 + o - k];
        }
        #pragma unroll
        for (int t = 0; t < 4; t++) {
            out4[8 * tid + 4 * h + t] = make_float4(inv * av[4 * t], inv * av[4 * t + 1],
                                                    inv * av[4 * t + 2], inv * av[4 * t + 3]);
        }
    }
}

// ---------------- launch ----------------
extern "C" void kernel_launch(void* const* d_in, const int* in_sizes, int n_in,
                              void* d_out, int out_size, void* d_ws, size_t ws_size,
                              hipStream_t stream) {
    const float* x  = (const float*)d_in[0];   // [1024][4096]
    const float* W  = (const float*)d_in[1];   // [8192][4096]
    const float* qp = (const float*)d_in[2];   // [39]
    float* out = (float*)d_out;                // [1024][8192] floats (Re of amps)
    long out_n = (long)out_size;

    const size_t need = (size_t)BATCH * IN_DIM * 2 + (size_t)HV * IN_DIM * 2;  // 72 MB

    if (ws_size >= need) {
        _Float16* xh = (_Float16*)d_ws;
        _Float16* wh = xh + (size_t)BATCH * IN_DIM;
        float* taps = nullptr;
        if (ws_size >= need + 256) {
            taps = (float*)((char*)d_ws + need);
            compute_taps<<<1, 64, 0, stream>>>(qp, taps);
        }
        int n4x = BATCH * IN_DIM / 4;          // 1,048,576
        int n4w = HV * IN_DIM / 4;             // 8,388,608
        cvt_f32_f16<<<n4x / 256, 256, 0, stream>>>((const float4*)x, (half4v*)xh, n4x);
        cvt_f32_f16<<<n4w / 256, 256, 0, stream>>>((const float4*)W, (half4v*)wh, n4w);
        dim3 grid2(HV / BN2, BATCH / BM2);     // (32, 8) = 256 blocks = 1/CU
        gemm_f16<<<grid2, 512, 0, stream>>>(xh, wh, out, out_n);
        norm_conv<<<BATCH, 256, 0, stream>>>(out, qp, taps, out_n);
    } else {
        float* taps = nullptr;
        if (ws_size >= 256) {
            taps = (float*)d_ws;
            compute_taps<<<1, 64, 0, stream>>>(qp, taps);
        }
        dim3 grid(HV / BN, BATCH / BM);        // (64, 8)
        gemm_f32in<<<grid, 256, 0, stream>>>(x, W, out, out_n);
        norm_conv<<<BATCH, 256, 0, stream>>>(out, qp, taps, out_n);
    }
}